// Round 2
// baseline (3189.051 us; speedup 1.0000x reference)
//
#include <hip/hip_runtime.h>
#include <hip/hip_bf16.h>

#define B_ 4
#define C_ 4
#define T_ 4096
#define H_ 256
#define INNER_ 512
#define S_ 64
#define L_ 3
#define V_ 1024
#define NTOK (B_*T_)   // 16384

__device__ __forceinline__ float siluf(float x) { return x / (1.0f + expf(-x)); }

// ---------------- embedding: A[n,h] = mean_c tok_emb[c,tok,h] + pos + text -------------
__global__ __launch_bounds__(256) void k_embed(
    const int* __restrict__ tok, const float* __restrict__ text,
    const float* __restrict__ tok_emb, const float* __restrict__ pos_emb,
    const int* __restrict__ pos_off, float* __restrict__ A)
{
    int gid = blockIdx.x * 256 + threadIdx.x;
    int h = gid & (H_ - 1);
    int n = gid >> 8;
    int b = n >> 12, t = n & (T_ - 1);
    float acc = 0.f;
#pragma unroll
    for (int c = 0; c < C_; ++c) {
        int tk = tok[((b * C_ + c) << 12) + t];
        acc += tok_emb[(c * V_ + tk) * H_ + h];
    }
    int po = pos_off[0];
    acc = acc * 0.25f + pos_emb[(po + t) * H_ + h] + text[b * H_ + h];
    A[n * H_ + h] = acc;
}

// ---------------- generic tiled GEMM: C(N,M) = A(N,K) * Bw(M,K)^T ----------------------
// grid.x = N/64, grid.y = M/64. All dims divisible (N=16384, M in {64,256,1024}, K in {256,512}).
__global__ __launch_bounds__(256) void gemm_bt(
    const float* __restrict__ A, int lda,
    const float* __restrict__ Bw, int ldb,
    float* __restrict__ C, int ldc,
    int K, int ACC)
{
    __shared__ float As[16][65];
    __shared__ float Bs[16][65];
    int tid = threadIdx.x;
    int tx = tid & 15, ty = tid >> 4;
    int n0 = blockIdx.x * 64, m0 = blockIdx.y * 64;
    float acc[4][4] = {};
    for (int k0 = 0; k0 < K; k0 += 16) {
#pragma unroll
        for (int q = 0; q < 4; ++q) {
            int idx = tid + q * 256;
            int row = idx >> 4, kk = idx & 15;
            As[kk][row] = A[(n0 + row) * lda + k0 + kk];
            Bs[kk][row] = Bw[(m0 + row) * ldb + k0 + kk];
        }
        __syncthreads();
#pragma unroll
        for (int kk = 0; kk < 16; ++kk) {
            float a[4], bb[4];
#pragma unroll
            for (int i = 0; i < 4; ++i) a[i] = As[kk][ty * 4 + i];
#pragma unroll
            for (int j = 0; j < 4; ++j) bb[j] = Bs[kk][tx * 4 + j];
#pragma unroll
            for (int i = 0; i < 4; ++i)
#pragma unroll
                for (int j = 0; j < 4; ++j)
                    acc[i][j] += a[i] * bb[j];
        }
        __syncthreads();
    }
#pragma unroll
    for (int i = 0; i < 4; ++i) {
        int r = n0 + ty * 4 + i;
#pragma unroll
        for (int j = 0; j < 4; ++j) {
            int cidx = r * ldc + m0 + tx * 4 + j;
            C[cidx] = (ACC ? C[cidx] : 0.f) + acc[i][j];
        }
    }
}

// ---------------- head GEMM: out[b,c,t,v] = fused[n,h]*head_w[c,v,h] + head_b ----------
__global__ __launch_bounds__(256) void gemm_head(
    const float* __restrict__ A,          // (16384, 256)
    const float* __restrict__ Bw,         // (1024, 256) for this c
    const float* __restrict__ bias,       // (1024,)
    float* __restrict__ out, int c)
{
    __shared__ float As[16][65];
    __shared__ float Bs[16][65];
    int tid = threadIdx.x;
    int tx = tid & 15, ty = tid >> 4;
    int n0 = blockIdx.x * 64, m0 = blockIdx.y * 64;
    float acc[4][4] = {};
    for (int k0 = 0; k0 < H_; k0 += 16) {
#pragma unroll
        for (int q = 0; q < 4; ++q) {
            int idx = tid + q * 256;
            int row = idx >> 4, kk = idx & 15;
            As[kk][row] = A[(n0 + row) * H_ + k0 + kk];
            Bs[kk][row] = Bw[(m0 + row) * H_ + k0 + kk];
        }
        __syncthreads();
#pragma unroll
        for (int kk = 0; kk < 16; ++kk) {
            float a[4], bb[4];
#pragma unroll
            for (int i = 0; i < 4; ++i) a[i] = As[kk][ty * 4 + i];
#pragma unroll
            for (int j = 0; j < 4; ++j) bb[j] = Bs[kk][tx * 4 + j];
#pragma unroll
            for (int i = 0; i < 4; ++i)
#pragma unroll
                for (int j = 0; j < 4; ++j)
                    acc[i][j] += a[i] * bb[j];
        }
        __syncthreads();
    }
#pragma unroll
    for (int i = 0; i < 4; ++i) {
        int n = n0 + ty * 4 + i;
        int b = n >> 12, t = n & (T_ - 1);
        int orow = (b * C_ + c) * T_ + t;
#pragma unroll
        for (int j = 0; j < 4; ++j) {
            int col = m0 + tx * 4 + j;
            out[(size_t)orow * V_ + col] = acc[i][j] + bias[col];
        }
    }
}

// ---------------- causal depthwise conv4 + bias + silu ---------------------------------
__global__ __launch_bounds__(256) void k_conv(
    const float* __restrict__ XP, const float* __restrict__ cw,
    const float* __restrict__ cb, float* __restrict__ XC)
{
    int gid = blockIdx.x * 256 + threadIdx.x;
    int i = gid & (INNER_ - 1);
    int n = gid >> 9;
    int b = n >> 12, t = n & (T_ - 1);
    float acc = cb[i];
#pragma unroll
    for (int k = 0; k < 4; ++k) {
        int tt = t - 3 + k;
        if (tt >= 0) acc += XP[((b << 12) + tt) * 1024 + i] * cw[i * 4 + k];
    }
    XC[n * INNER_ + i] = siluf(acc);
}

// ---------------- sequential EWMA scan, in place over U (N,S) --------------------------
__global__ void k_scan(float* __restrict__ U)
{
    int b = blockIdx.x, s = threadIdx.x;
    float h = 0.f;
    float* p = U + (size_t)(b << 12) * S_ + s;
    for (int t = 0; t < T_; ++t) {
        h = 0.95f * h + 0.05f * p[t * S_];
        p[t * S_] = h;
    }
}

// ---------------- y2 = (hs@Cp^T + D*xc) * silu(xg), in place over XC -------------------
__global__ __launch_bounds__(256) void k_ymix(
    const float* __restrict__ HS,         // (N,64)
    const float* __restrict__ Cp,         // (512,64)
    const float* __restrict__ Dp,         // (512,)
    float* __restrict__ XC,               // (N,512) xc in, y2 out
    const float* __restrict__ XP)         // (N,1024), xg at col 512+
{
    const int NB = 4;
    int n0 = blockIdx.x * NB;
    __shared__ float hsL[NB * 64];
    int tid = threadIdx.x;
    {
        int nn = tid >> 6, s = tid & 63;
        hsL[tid] = HS[(n0 + nn) * 64 + s];
    }
    __syncthreads();
#pragma unroll
    for (int half = 0; half < 2; ++half) {
        int i = tid + half * 256;
        float acc[NB] = {};
        const float* cp = Cp + i * 64;
        for (int s = 0; s < 64; ++s) {
            float w = cp[s];
#pragma unroll
            for (int nn = 0; nn < NB; ++nn) acc[nn] += hsL[nn * 64 + s] * w;
        }
        float d = Dp[i];
#pragma unroll
        for (int nn = 0; nn < NB; ++nn) {
            int n = n0 + nn;
            float xc = XC[n * INNER_ + i];
            float xg = XP[n * 1024 + 512 + i];
            XC[n * INNER_ + i] = (acc[nn] + d * xc) * siluf(xg);
        }
    }
}

// ---------------- residual + LayerNorm (block per token) -------------------------------
__global__ __launch_bounds__(256) void k_ln(
    const float* __restrict__ Yo, const float* __restrict__ Xin,
    const float* __restrict__ g, const float* __restrict__ bb,
    float* __restrict__ Out)
{
    int n = blockIdx.x, h = threadIdx.x;
    float x = Yo[n * H_ + h] + Xin[n * H_ + h];
    float s = x, sq = x * x;
#pragma unroll
    for (int off = 32; off >= 1; off >>= 1) {
        s  += __shfl_down(s, off, 64);
        sq += __shfl_down(sq, off, 64);
    }
    __shared__ float rs[4], rq[4];
    int wid = h >> 6, lane = h & 63;
    if (lane == 0) { rs[wid] = s; rq[wid] = sq; }
    __syncthreads();
    float S = rs[0] + rs[1] + rs[2] + rs[3];
    float Q = rq[0] + rq[1] + rq[2] + rq[3];
    float m = S * (1.f / H_);
    float v = fmaxf(Q * (1.f / H_) - m * m, 0.f);
    float r = rsqrtf(v + 1e-5f);
    Out[n * H_ + h] = (x - m) * r * g[h] + bb[h];
}

// ---------------- relu(pre + fus_b) then LN --------------------------------------------
__global__ __launch_bounds__(256) void k_fusln(
    const float* __restrict__ Pre, const float* __restrict__ fb,
    const float* __restrict__ fg, const float* __restrict__ fbb,
    float* __restrict__ Out)
{
    int n = blockIdx.x, h = threadIdx.x;
    float x = fmaxf(Pre[n * H_ + h] + fb[h], 0.f);
    float s = x, sq = x * x;
#pragma unroll
    for (int off = 32; off >= 1; off >>= 1) {
        s  += __shfl_down(s, off, 64);
        sq += __shfl_down(sq, off, 64);
    }
    __shared__ float rs[4], rq[4];
    int wid = h >> 6, lane = h & 63;
    if (lane == 0) { rs[wid] = s; rq[wid] = sq; }
    __syncthreads();
    float S = rs[0] + rs[1] + rs[2] + rs[3];
    float Q = rq[0] + rq[1] + rq[2] + rq[3];
    float m = S * (1.f / H_);
    float v = fmaxf(Q * (1.f / H_) - m * m, 0.f);
    float r = rsqrtf(v + 1e-5f);
    Out[n * H_ + h] = (x - m) * r * fg[h] + fbb[h];
}

// ---------------- 4 dilated pattern convs (block = 4 consecutive t of one b) -----------
__global__ __launch_bounds__(256) void k_pat(
    const float* __restrict__ A, const float* __restrict__ pw,
    const float* __restrict__ pb, float* __restrict__ PAT)
{
    __shared__ float Lr[28 * 256];
    int g = blockIdx.x;
    int b = g >> 10;
    int t0 = (g & 1023) << 2;
    int tid = threadIdx.x;
    for (int idx = tid; idx < 28 * 256; idx += 256) {
        int r = idx >> 8, h = idx & 255;
        int t = t0 - 12 + r;
        Lr[idx] = (t >= 0 && t < T_) ? A[((b << 12) + t) * H_ + h] : 0.f;
    }
    __syncthreads();
    const int dils[4] = {1, 3, 6, 12};
    int id = tid >> 6, o = tid & 63;
    int d = dils[id];
    const float* w = pw + (id * 64 + o) * 256 * 3;
    float bias = pb[id * 64 + o];
    float a0 = bias, a1 = bias, a2 = bias, a3 = bias;
    for (int cin = 0; cin < 256; ++cin) {
        float w0 = w[cin * 3 + 0];
        float w1 = w[cin * 3 + 1];
        float w2 = w[cin * 3 + 2];
        a0 += Lr[(12 - d) * 256 + cin] * w0 + Lr[12 * 256 + cin] * w1 + Lr[(12 + d) * 256 + cin] * w2;
        a1 += Lr[(13 - d) * 256 + cin] * w0 + Lr[13 * 256 + cin] * w1 + Lr[(13 + d) * 256 + cin] * w2;
        a2 += Lr[(14 - d) * 256 + cin] * w0 + Lr[14 * 256 + cin] * w1 + Lr[(14 + d) * 256 + cin] * w2;
        a3 += Lr[(15 - d) * 256 + cin] * w0 + Lr[15 * 256 + cin] * w1 + Lr[(15 + d) * 256 + cin] * w2;
    }
    int col = id * 64 + o;
    PAT[((b << 12) + t0 + 0) * H_ + col] = a0;
    PAT[((b << 12) + t0 + 1) * H_ + col] = a1;
    PAT[((b << 12) + t0 + 2) * H_ + col] = a2;
    PAT[((b << 12) + t0 + 3) * H_ + col] = a3;
}

extern "C" void kernel_launch(void* const* d_in, const int* in_sizes, int n_in,
                              void* d_out, int out_size, void* d_ws, size_t ws_size,
                              hipStream_t stream)
{
    (void)in_sizes; (void)n_in; (void)out_size; (void)ws_size;
    const int*   tok      = (const int*)d_in[0];
    const float* text     = (const float*)d_in[1];
    const float* tok_emb  = (const float*)d_in[2];
    const float* pos_emb  = (const float*)d_in[3];
    const float* in_w     = (const float*)d_in[4];
    const float* conv_w   = (const float*)d_in[5];
    const float* conv_b   = (const float*)d_in[6];
    const float* Dw       = (const float*)d_in[7];
    const float* Bp_w     = (const float*)d_in[8];
    const float* Cp_w     = (const float*)d_in[9];
    const float* out_w    = (const float*)d_in[10];
    const float* ln_g     = (const float*)d_in[11];
    const float* ln_b     = (const float*)d_in[12];
    const float* pat_w    = (const float*)d_in[13];
    const float* pat_b    = (const float*)d_in[14];
    const float* fus_w    = (const float*)d_in[15];
    const float* fus_b    = (const float*)d_in[16];
    const float* fus_g    = (const float*)d_in[17];
    const float* fus_bb   = (const float*)d_in[18];
    const float* head_w   = (const float*)d_in[19];
    const float* head_b   = (const float*)d_in[20];
    const int*   pos_off  = (const int*)d_in[21];

    float* W    = (float*)d_ws;
    float* Abuf = W;                    //  4,194,304 f (audio_emb; later FUSED)
    float* F0   = Abuf + 4194304;       //  4,194,304 f
    float* F1   = F0 + 4194304;         //  4,194,304 f
    float* XP   = F1 + 4194304;         // 16,777,216 f (xp; later FUSP in [0,4M), PATb in [8M,12M))
    float* XC   = XP + 16777216;        //  8,388,608 f (xc; then y2 in place)
    float* U    = XC + 8388608;         //  1,048,576 f (u; then hs in place)
    // total: 38,797,312 floats = 148 MiB

    k_embed<<<NTOK * H_ / 256, 256, 0, stream>>>(tok, text, tok_emb, pos_emb, pos_off, Abuf);

    const float* fin = Abuf;
    float* fouts[3] = {F0, F1, F0};
    for (int l = 0; l < L_; ++l) {
        float* fout = fouts[l];
        gemm_bt<<<dim3(NTOK / 64, 1024 / 64), 256, 0, stream>>>(
            fin, H_, in_w + l * 1024 * H_, H_, XP, 1024, H_, 0);
        k_conv<<<NTOK * INNER_ / 256, 256, 0, stream>>>(
            XP, conv_w + l * INNER_ * 4, conv_b + l * INNER_, XC);
        gemm_bt<<<dim3(NTOK / 64, 1), 256, 0, stream>>>(
            XC, INNER_, Bp_w + l * S_ * INNER_, INNER_, U, S_, INNER_, 0);
        k_scan<<<B_, S_, 0, stream>>>(U);
        k_ymix<<<NTOK / 4, 256, 0, stream>>>(
            U, Cp_w + l * INNER_ * S_, Dw + l * INNER_, XC, XP);
        gemm_bt<<<dim3(NTOK / 64, H_ / 64), 256, 0, stream>>>(
            XC, INNER_, out_w + l * H_ * INNER_, INNER_, fout, H_, INNER_, 0);
        k_ln<<<NTOK, 256, 0, stream>>>(fout, fin, ln_g + l * H_, ln_b + l * H_, fout);
        fin = fout;
    }
    // fin == F0 holds final feat
    float* PATb = XP + 8388608;
    k_pat<<<B_ * (T_ / 4), 256, 0, stream>>>(Abuf, pat_w, pat_b, PATb);

    float* FUSP = XP;
    gemm_bt<<<dim3(NTOK / 64, H_ / 64), 256, 0, stream>>>(
        fin, H_, fus_w, 2 * H_, FUSP, H_, H_, 0);
    gemm_bt<<<dim3(NTOK / 64, H_ / 64), 256, 0, stream>>>(
        PATb, H_, fus_w + H_, 2 * H_, FUSP, H_, H_, 1);
    float* FUSED = Abuf;
    k_fusln<<<NTOK, 256, 0, stream>>>(FUSP, fus_b, fus_g, fus_bb, FUSED);

    for (int c = 0; c < C_; ++c) {
        gemm_head<<<dim3(NTOK / 64, V_ / 64), 256, 0, stream>>>(
            FUSED, head_w + c * V_ * H_, head_b + c * V_, (float*)d_out, c);
    }
}